// Round 4
// baseline (1089.212 us; speedup 1.0000x reference)
//
#include <hip/hip_runtime.h>
#include <hip/hip_bf16.h>
#include <math.h>

#define BSZ 8
#define NLVL 4
#define E 512
#define H 8
#define D 64
#define FFN 2048
#define NNZ 131072
#define NQ 32
#define P32 32
#define NCH 128           // key chunks per batch (128 keys each)
#define NEGF -3.0e38f

typedef __attribute__((ext_vector_type(8))) short bf16x8;
typedef __attribute__((ext_vector_type(4))) float f32x4;

// ws layout (float offsets). ints counts_b[8], off_b[8] at front.
#define WS_QROT   16
#define WS_WSUM   (WS_QROT + NQ*E)
#define WS_OATT   (WS_WSUM + BSZ*P32*E)
#define WS_O2     (WS_OATT + NQ*E)
#define WS_Y      (WS_O2 + NQ*E)
#define WS_HID    (WS_Y + NQ*E)
#define WS_PART   (WS_HID + NQ*FFN)              // [BSZ*NCH][32 p][512 e] f32
#define WS_ML     (WS_PART + BSZ*NCH*P32*E)      // [BSZ*NCH][32][2] f32
#define WS_WALL   (WS_ML + BSZ*NCH*P32*2)        // bf16 [b][128][512] (shorts)

__device__ inline short f2bf(float x) {
    __hip_bfloat16 h = __float2bfloat16(x);
    union { __hip_bfloat16 v; short s; } u; u.v = h; return u.s;
}

__device__ inline bf16x8 cvt8(const float* p) {
    float4 x = *(const float4*)p;
    float4 y = *(const float4*)(p + 4);
    union { bf16x8 v; __hip_bfloat162 h[4]; } u;
    u.h[0] = __float22bfloat162_rn(float2{x.x, x.y});
    u.h[1] = __float22bfloat162_rn(float2{x.z, x.w});
    u.h[2] = __float22bfloat162_rn(float2{y.x, y.y});
    u.h[3] = __float22bfloat162_rn(float2{y.z, y.w});
    return u.v;
}

// ---------------- tiny setup kernels ----------------
__global__ void k_zero(int* wsi) {
    if (blockIdx.x == 0 && threadIdx.x < 8) wsi[threadIdx.x] = 0;
}

__global__ void k_hist(const int* __restrict__ fb, int* wsi) {
    __shared__ int h[8];
    int t = threadIdx.x;
    if (t < 8) h[t] = 0;
    __syncthreads();
    for (int j = blockIdx.x * 256 + t; j < NNZ; j += gridDim.x * 256)
        atomicAdd(&h[fb[j]], 1);
    __syncthreads();
    if (t < 8) atomicAdd(&wsi[t], h[t]);
}

__global__ void k_off(int* wsi) {
    if (threadIdx.x == 0) {
        int run = 0;
        for (int b = 0; b < 8; b++) { wsi[8 + b] = run; run += wsi[b]; }
    }
}

// ---------------- q = rope(LN(bg) @ Wq) ----------------
__global__ void k_qrot(const float* __restrict__ bg, const float* __restrict__ Wq,
                       const float* __restrict__ rf, const float* __restrict__ g,
                       const float* __restrict__ bb, float* __restrict__ ws) {
    __shared__ float xr[E];
    __shared__ float qrow[E];
    __shared__ float red[8];
    int r = blockIdx.x, t = threadIdx.x;
    float v0 = bg[r * E + t], v1 = bg[r * E + t + 256];
    float s = v0 + v1;
    for (int o = 32; o > 0; o >>= 1) s += __shfl_down(s, o, 64);
    if ((t & 63) == 0) red[t >> 6] = s;
    __syncthreads();
    if (t == 0) red[0] = (red[0] + red[1] + red[2] + red[3]) * (1.0f / E);
    __syncthreads();
    float mu = red[0];
    __syncthreads();
    float d0 = v0 - mu, d1 = v1 - mu;
    s = d0 * d0 + d1 * d1;
    for (int o = 32; o > 0; o >>= 1) s += __shfl_down(s, o, 64);
    if ((t & 63) == 0) red[t >> 6] = s;
    __syncthreads();
    if (t == 0) red[0] = rsqrtf((red[0] + red[1] + red[2] + red[3]) * (1.0f / E) + 1e-5f);
    __syncthreads();
    float rstd = red[0];
    xr[t] = d0 * rstd * g[t] + bb[t];
    xr[t + 256] = d1 * rstd * g[t + 256] + bb[t + 256];
    __syncthreads();
    for (int half = 0; half < 2; half++) {
        int c = t + half * 256;
        float acc = 0.f;
        for (int e = 0; e < E; e++) acc += xr[e] * Wq[e * E + c];
        qrow[c] = acc;
    }
    __syncthreads();
    int c0 = 2 * t, c1 = c0 + 1;
    int h = c0 >> 6, ii = (c0 & 63) >> 1;
    float freq = rf[h * 32 + ii];
    float pos = (float)(r >> 3);
    float a = pos * freq, ca = cosf(a), sa = sinf(a);
    float x1 = qrow[c0], x2 = qrow[c1];
    float* qr = ws + WS_QROT + r * E;
    qr[c0] = x1 * ca - x2 * sa;
    qr[c1] = x1 * sa + x2 * ca;
}

// ---------------- Wall_bf[b][n=lvl*32+l*8+h][e] ----------------
__global__ void k_wtil(const float* __restrict__ Wkv, const float* __restrict__ rf,
                       const float* __restrict__ ws, short* __restrict__ wall) {
    __shared__ float u[D];
    int blk = blockIdx.x;
    int h = blk & 7, lvl = (blk >> 3) & 3, r = blk >> 5;
    int b = r >> 2, l = r & 3;
    int t = threadIdx.x;
    const float* qr = ws + WS_QROT + r * E + h * D;
    if (t < 32) {
        float freq = rf[h * 32 + t];
        float a = (float)lvl * freq;
        float ca = cosf(a), sa = sinf(a);
        float x1 = qr[2 * t], x2 = qr[2 * t + 1];
        u[2 * t] = x1 * ca + x2 * sa;
        u[2 * t + 1] = -x1 * sa + x2 * ca;
    }
    __syncthreads();
    int n = lvl * 32 + l * 8 + h;
    short* wrow_out = wall + ((size_t)(b * 128 + n)) * E;
    for (int rep = 0; rep < 8; rep++) {
        int e = t + rep * 64;
        const float* wrow = Wkv + (size_t)e * (2 * E) + h * D;
        float acc = 0.f;
#pragma unroll
        for (int c = 0; c < D; c++) acc += wrow[c] * u[c];
        wrow_out[e] = f2bf(acc * 0.125f);
    }
}

// ---------------- fused flash attention ----------------
// Grid (b=8, kc=128 chunks of 128 keys). 256 thr = 4 waves.
// Wave w: scores rows = wall[b][w*32..w*32+32) (level w), PV e-strip [w*128,(w+1)*128).
// Per 32-key sub-step: per-wave fvT staging (no barrier), scores B from global,
// register-resident online softmax (mbuf broadcast), 2 barriers total.
#define TSTR 40    // fvT/pbuf key-stride (shorts)
__global__ __launch_bounds__(256, 3) void k_flash(
    const float* __restrict__ fv, const int* __restrict__ fl,
    const short* __restrict__ wall, const int* __restrict__ wsi,
    const int* __restrict__ maxlen, float* __restrict__ part, float* __restrict__ ml) {
    __shared__ short fvT[512 * TSTR];    // 4 per-wave strips of [128 e][32 keys]
    __shared__ short pbuf[32 * TSTR];    // [p][key] bf16
    __shared__ float mbuf[32 * 4];       // [p][wave]
    __shared__ float lfin[32 * 4];
    __shared__ float mfin[32];

    int t = threadIdx.x;
    int w = t >> 6, lane = t & 63, col = lane & 15, quad = lane >> 4;
    int b = blockIdx.x, kc = blockIdx.y;
    int cnt = wsi[b], mlen = maxlen[0];
    int lim = cnt < mlen ? cnt : mlen;
    int off = wsi[8 + b];
    int kbase = kc * 128;
    int nv = lim - kbase; if (nv > 128) nv = 128; if (nv < 0) nv = 0;

    f32x4 acc_o[2][8];
#pragma unroll
    for (int mt = 0; mt < 2; mt++)
#pragma unroll
        for (int nt = 0; nt < 8; nt++) acc_o[mt][nt] = f32x4{0.f, 0.f, 0.f, 0.f};
    float mrun[2][4], lrun[2][4];
#pragma unroll
    for (int mt = 0; mt < 2; mt++)
#pragma unroll
        for (int r = 0; r < 4; r++) { mrun[mt][r] = NEGF; lrun[mt][r] = 0.f; }

    const short* wallb = wall + (size_t)b * 128 * E;
    short* fvTw = &fvT[(size_t)w * 128 * TSTR];
    int k2 = lane & 15;           // staging: key pair 2*k2, 2*k2+1
    int eseg = lane >> 4;         // staging: 32-e segment within wave strip

    for (int s = 0; s < 4; s++) {
        if (s * 32 >= nv) break;
        int j0 = off + kbase + s * 32;
        // ---- stage own e-strip of 32 keys into fvT (per-wave; no barrier) ----
        {
            int g0 = j0 + 2 * k2, g1 = g0 + 1;
            if (g0 > NNZ - 1) g0 = NNZ - 1;
            if (g1 > NNZ - 1) g1 = NNZ - 1;
            const float* r0 = fv + (size_t)g0 * E + w * 128 + eseg * 32;
            const float* r1 = fv + (size_t)g1 * E + w * 128 + eseg * 32;
            short* dst = fvTw + (size_t)(eseg * 32) * TSTR + 2 * k2;
#pragma unroll
            for (int i = 0; i < 8; i++) {
                float4 x0 = *(const float4*)(r0 + i * 4);
                float4 x1 = *(const float4*)(r1 + i * 4);
                *(__hip_bfloat162*)&dst[(i * 4 + 0) * TSTR] = __float22bfloat162_rn(float2{x0.x, x1.x});
                *(__hip_bfloat162*)&dst[(i * 4 + 1) * TSTR] = __float22bfloat162_rn(float2{x0.y, x1.y});
                *(__hip_bfloat162*)&dst[(i * 4 + 2) * TSTR] = __float22bfloat162_rn(float2{x0.z, x1.z});
                *(__hip_bfloat162*)&dst[(i * 4 + 3) * TSTR] = __float22bfloat162_rn(float2{x0.w, x1.w});
            }
        }
        // ---- scores MFMA: A=wall (global, L2-hot), B=fv (global f32->bf16) ----
        f32x4 acc_s[2][2];
#pragma unroll
        for (int mt = 0; mt < 2; mt++)
#pragma unroll
            for (int kt = 0; kt < 2; kt++) acc_s[mt][kt] = f32x4{0.f, 0.f, 0.f, 0.f};
        {
            const short* wr0 = wallb + (size_t)(w * 32 + col) * E + quad * 8;
            const short* wr1 = wr0 + (size_t)16 * E;
            const float* fb0 = fv + (size_t)(j0 + col) * E + quad * 8;
            const float* fb1 = fv + (size_t)(j0 + 16 + col) * E + quad * 8;
#pragma unroll
            for (int ks = 0; ks < 16; ks++) {
                int e0 = ks * 32;
                bf16x8 A0 = *(const bf16x8*)(wr0 + e0);
                bf16x8 A1 = *(const bf16x8*)(wr1 + e0);
                bf16x8 B0 = cvt8(fb0 + e0);
                bf16x8 B1 = cvt8(fb1 + e0);
                acc_s[0][0] = __builtin_amdgcn_mfma_f32_16x16x32_bf16(A0, B0, acc_s[0][0], 0, 0, 0);
                acc_s[0][1] = __builtin_amdgcn_mfma_f32_16x16x32_bf16(A0, B1, acc_s[0][1], 0, 0, 0);
                acc_s[1][0] = __builtin_amdgcn_mfma_f32_16x16x32_bf16(A1, B0, acc_s[1][0], 0, 0, 0);
                acc_s[1][1] = __builtin_amdgcn_mfma_f32_16x16x32_bf16(A1, B1, acc_s[1][1], 0, 0, 0);
            }
        }
        // ---- per-wave sub-step max per plane -> mbuf ----
        int kg0 = j0 + col, kg1 = j0 + 16 + col;
        if (kg0 > NNZ - 1) kg0 = NNZ - 1;
        if (kg1 > NNZ - 1) kg1 = NNZ - 1;
        int lv0 = fl[kg0], lv1 = fl[kg1];
        bool valid0 = (s * 32 + col) < nv;
        bool valid1 = (s * 32 + 16 + col) < nv;
        bool sel0 = valid0 && (lv0 == w);
        bool sel1 = valid1 && (lv1 == w);
#pragma unroll
        for (int mt = 0; mt < 2; mt++)
#pragma unroll
            for (int r = 0; r < 4; r++) {
                float v0 = sel0 ? acc_s[mt][0][r] : NEGF;
                float v1 = sel1 ? acc_s[mt][1][r] : NEGF;
                float v = fmaxf(v0, v1);
#pragma unroll
                for (int msk = 1; msk < 16; msk <<= 1) v = fmaxf(v, __shfl_xor(v, msk, 16));
                if (col == 0) mbuf[(mt * 16 + quad * 4 + r) * 4 + w] = v;
            }
        __syncthreads();   // B1: mbuf visible; also protects pbuf reuse from prev step
        // ---- combine max (redundant per lane), exp -> pbuf, rescale O ----
#pragma unroll
        for (int mt = 0; mt < 2; mt++)
#pragma unroll
            for (int r = 0; r < 4; r++) {
                int p = mt * 16 + quad * 4 + r;
                f32x4 mm = *(const f32x4*)&mbuf[p * 4];
                float mn = fmaxf(fmaxf(mm[0], mm[1]), fmaxf(mm[2], mm[3]));
                mn = fmaxf(mn, mrun[mt][r]);
                float al = expf(mrun[mt][r] - mn);
                mrun[mt][r] = mn;
                float add = 0.f;
                if (sel0) {
                    float pv = expf(acc_s[mt][0][r] - mn);
                    pbuf[p * TSTR + col] = f2bf(pv);
                    add += pv;
                } else if (w == 0 && !valid0) {
                    pbuf[p * TSTR + col] = 0;
                }
                if (sel1) {
                    float pv = expf(acc_s[mt][1][r] - mn);
                    pbuf[p * TSTR + 16 + col] = f2bf(pv);
                    add += pv;
                } else if (w == 0 && !valid1) {
                    pbuf[p * TSTR + 16 + col] = 0;
                }
                lrun[mt][r] = lrun[mt][r] * al + add;
#pragma unroll
                for (int nt = 0; nt < 8; nt++) acc_o[mt][nt][r] *= al;
            }
        __syncthreads();   // B2: pbuf complete
        // ---- PV MFMA: O[p][e-strip] += P~ @ fvT (own strip; no extra barrier) ----
        {
            bf16x8 Ap0 = *(const bf16x8*)&pbuf[col * TSTR + quad * 8];
            bf16x8 Ap1 = *(const bf16x8*)&pbuf[(16 + col) * TSTR + quad * 8];
            const short* bt = fvTw + (size_t)col * TSTR + quad * 8;
#pragma unroll
            for (int nt = 0; nt < 8; nt++) {
                bf16x8 Bf = *(const bf16x8*)(bt + (size_t)(nt * 16) * TSTR);
                acc_o[0][nt] = __builtin_amdgcn_mfma_f32_16x16x32_bf16(Ap0, Bf, acc_o[0][nt], 0, 0, 0);
                acc_o[1][nt] = __builtin_amdgcn_mfma_f32_16x16x32_bf16(Ap1, Bf, acc_o[1][nt], 0, 0, 0);
            }
        }
    }
    // ---- epilogue ----
#pragma unroll
    for (int mt = 0; mt < 2; mt++)
#pragma unroll
        for (int r = 0; r < 4; r++) {
            float ls = lrun[mt][r];
#pragma unroll
            for (int msk = 1; msk < 16; msk <<= 1) ls += __shfl_xor(ls, msk, 16);
            int p = mt * 16 + quad * 4 + r;
            if (col == 0) {
                lfin[p * 4 + w] = ls;
                if (w == 0) mfin[p] = mrun[mt][r];
            }
        }
    size_t pbase = ((size_t)(b * NCH + kc) * P32) * E;
#pragma unroll
    for (int mt = 0; mt < 2; mt++)
#pragma unroll
        for (int r = 0; r < 4; r++) {
            int p = mt * 16 + quad * 4 + r;
#pragma unroll
            for (int nt = 0; nt < 8; nt++) {
                int e = w * 128 + nt * 16 + col;
                part[pbase + (size_t)p * E + e] = acc_o[mt][nt][r];
            }
        }
    __syncthreads();
    if (t < 32) {
        float l = lfin[t * 4] + lfin[t * 4 + 1] + lfin[t * 4 + 2] + lfin[t * 4 + 3];
        size_t idx = (size_t)(b * NCH + kc) * P32 + t;
        ml[idx * 2] = mfin[t];
        ml[idx * 2 + 1] = l;
    }
}

// ---------------- merge chunk partials -> wsum[b*32+p][e] ----------------
__global__ void k_merge(const float* __restrict__ part, const float* __restrict__ ml,
                        float* __restrict__ wsum) {
    __shared__ float wexp[NCH];
    int b = blockIdx.x >> 5, p = blockIdx.x & 31;
    int t = threadIdx.x;
    float M = NEGF;
    for (int kc = 0; kc < NCH; kc++)
        M = fmaxf(M, ml[((size_t)(b * NCH + kc) * P32 + p) * 2]);
    float denom = 0.f;
    for (int kc = 0; kc < NCH; kc++) {
        size_t idx = ((size_t)(b * NCH + kc) * P32 + p) * 2;
        denom += ml[idx + 1] * expf(ml[idx] - M);
    }
    if (t < NCH)
        wexp[t] = expf(ml[((size_t)(b * NCH + t) * P32 + p) * 2] - M);
    __syncthreads();
    float inv = 1.0f / denom;
    for (int half = 0; half < 2; half++) {
        int e = t + half * 256;
        float acc = 0.f;
        for (int kc = 0; kc < NCH; kc++)
            acc += part[((size_t)(b * NCH + kc) * P32 + p) * E + e] * wexp[kc];
        wsum[((size_t)(b * P32 + p)) * E + e] = acc * inv;
    }
}

// ---------------- o_attn[r][c] = wsum[b][l*8+h] . Wv[:, h*64+ch] ----------------
__global__ void k_oproj(const float* __restrict__ wsum, const float* __restrict__ Wkv,
                        float* __restrict__ oatt) {
    __shared__ float Aw[NQ][E];
    int h = blockIdx.x >> 2, ct = blockIdx.x & 3;
    int t = threadIdx.x;
    {
        int rr = t >> 3, x = (t & 7) * 64;
        int row = (rr >> 2) * P32 + (rr & 3) * 8 + h;
#pragma unroll
        for (int q4 = 0; q4 < 16; q4++)
            *(float4*)&Aw[rr][x + q4 * 4] = *(const float4*)&wsum[(size_t)row * E + x + q4 * 4];
    }
    __syncthreads();
#pragma unroll
    for (int rep = 0; rep < 2; rep++) {
        int idx = rep * 256 + t;
        int rr = idx >> 4, cl = idx & 15;
        int c = h * D + ct * 16 + cl;
        float acc = 0.f;
        for (int e = 0; e < E; e++) acc += Aw[rr][e] * Wkv[(size_t)e * (2 * E) + E + c];
        oatt[rr * E + c] = acc;
    }
}

// ---------------- o2 = o_attn @ Wo + bg ----------------
__global__ void k_wo(const float* __restrict__ oatt, const float* __restrict__ Wo,
                     const float* __restrict__ bg, float* __restrict__ o2) {
    __shared__ float Aw[NQ * E];
    int t = threadIdx.x;
#pragma unroll
    for (int q = 0; q < 16; q++) {
        int i = (q * 256 + t) * 4;
        *(float4*)&Aw[i] = *(const float4*)&oatt[i];
    }
    __syncthreads();
    int ct = blockIdx.x;
#pragma unroll
    for (int rep = 0; rep < 4; rep++) {
        int idx = rep * 256 + t;
        int rr = idx >> 5, cl = idx & 31;
        int c = ct * 32 + cl;
        float acc = bg[rr * E + c];
        for (int e = 0; e < E; e++) acc += Aw[rr * E + e] * Wo[(size_t)e * E + c];
        o2[rr * E + c] = acc;
    }
}

// ---------------- LN rows of o2 -> y ----------------
__global__ void k_ln2(const float* __restrict__ o2, const float* __restrict__ g,
                      const float* __restrict__ bb, float* __restrict__ y) {
    __shared__ float red[8];
    int r = blockIdx.x, t = threadIdx.x;
    float v0 = o2[r * E + t], v1 = o2[r * E + t + 256];
    float s = v0 + v1;
    for (int o = 32; o > 0; o >>= 1) s += __shfl_down(s, o, 64);
    if ((t & 63) == 0) red[t >> 6] = s;
    __syncthreads();
    if (t == 0) red[0] = (red[0] + red[1] + red[2] + red[3]) * (1.0f / E);
    __syncthreads();
    float mu = red[0];
    __syncthreads();
    float d0 = v0 - mu, d1 = v1 - mu;
    s = d0 * d0 + d1 * d1;
    for (int o = 32; o > 0; o >>= 1) s += __shfl_down(s, o, 64);
    if ((t & 63) == 0) red[t >> 6] = s;
    __syncthreads();
    if (t == 0) red[0] = rsqrtf((red[0] + red[1] + red[2] + red[3]) * (1.0f / E) + 1e-5f);
    __syncthreads();
    float rstd = red[0];
    y[r * E + t] = d0 * rstd * g[t] + bb[t];
    y[r * E + t + 256] = d1 * rstd * g[t + 256] + bb[t + 256];
}

// ---------------- hid = relu(y @ W1 + b1) ----------------
__global__ void k_ffn1(const float* __restrict__ y, const float* __restrict__ W1,
                       const float* __restrict__ b1, float* __restrict__ hid) {
    __shared__ float Aw[NQ * E];
    int t = threadIdx.x;
#pragma unroll
    for (int q = 0; q < 16; q++) {
        int i = (q * 256 + t) * 4;
        *(float4*)&Aw[i] = *(const float4*)&y[i];
    }
    __syncthreads();
    int ft = blockIdx.x;
#pragma unroll
    for (int rep = 0; rep < 4; rep++) {
        int idx = rep * 256 + t;
        int rr = idx >> 5, fl = idx & 31;
        int f = ft * 32 + fl;
        float acc = b1[f];
        for (int e = 0; e < E; e++) acc += Aw[rr * E + e] * W1[(size_t)e * FFN + f];
        hid[rr * FFN + f] = fmaxf(acc, 0.f);
    }
}

// ---------------- out = o2 + hid @ W2 + b2 ----------------
__global__ void k_ffn2(const float* __restrict__ hid, const float* __restrict__ W2,
                       const float* __restrict__ b2, const float* __restrict__ o2,
                       float* __restrict__ out) {
    int ct = blockIdx.x;
    int t = threadIdx.x;
#pragma unroll
    for (int rep = 0; rep < 2; rep++) {
        int idx = rep * 256 + t;
        int rr = idx >> 4, cl = idx & 15;
        int c = ct * 16 + cl;
        float acc = b2[c] + o2[rr * E + c];
        for (int f = 0; f < FFN; f++) acc += hid[rr * FFN + f] * W2[(size_t)f * E + c];
        out[rr * E + c] = acc;
    }
}

extern "C" void kernel_launch(void* const* d_in, const int* in_sizes, int n_in,
                              void* d_out, int out_size, void* d_ws, size_t ws_size,
                              hipStream_t stream) {
    const float* bg  = (const float*)d_in[0];
    const float* fv  = (const float*)d_in[1];
    const int*   fb  = (const int*)d_in[2];
    const int*   fl  = (const int*)d_in[3];
    const float* Wq  = (const float*)d_in[4];
    const float* Wkv = (const float*)d_in[5];
    const float* Wo  = (const float*)d_in[6];
    const float* rf  = (const float*)d_in[7];
    const float* lag = (const float*)d_in[8];
    const float* lab = (const float*)d_in[9];
    const float* lfg = (const float*)d_in[10];
    const float* lfb = (const float*)d_in[11];
    const float* W1  = (const float*)d_in[12];
    const float* b1  = (const float*)d_in[13];
    const float* W2  = (const float*)d_in[14];
    const float* b2  = (const float*)d_in[15];
    const int* maxlen = (const int*)d_in[16];
    float* ws = (float*)d_ws;
    int* wsi = (int*)d_ws;
    short* wall = (short*)(ws + WS_WALL);
    float* out = (float*)d_out;

    hipLaunchKernelGGL(k_zero, dim3(1), dim3(64), 0, stream, wsi);
    hipLaunchKernelGGL(k_hist, dim3(128), dim3(256), 0, stream, fb, wsi);
    hipLaunchKernelGGL(k_off, dim3(1), dim3(64), 0, stream, wsi);
    hipLaunchKernelGGL(k_qrot, dim3(NQ), dim3(256), 0, stream, bg, Wq, rf, lag, lab, ws);
    hipLaunchKernelGGL(k_wtil, dim3(NQ * NLVL * H), dim3(64), 0, stream, Wkv, rf, ws, wall);
    hipLaunchKernelGGL(k_flash, dim3(BSZ, NCH), dim3(256), 0, stream,
                       fv, fl, wall, wsi, maxlen, ws + WS_PART, ws + WS_ML);
    hipLaunchKernelGGL(k_merge, dim3(BSZ * P32), dim3(256), 0, stream,
                       ws + WS_PART, ws + WS_ML, ws + WS_WSUM);
    hipLaunchKernelGGL(k_oproj, dim3(H * 4), dim3(256), 0, stream,
                       ws + WS_WSUM, Wkv, ws + WS_OATT);
    hipLaunchKernelGGL(k_wo, dim3(16), dim3(256), 0, stream,
                       ws + WS_OATT, Wo, bg, ws + WS_O2);
    hipLaunchKernelGGL(k_ln2, dim3(NQ), dim3(256), 0, stream,
                       ws + WS_O2, lfg, lfb, ws + WS_Y);
    hipLaunchKernelGGL(k_ffn1, dim3(FFN / 32), dim3(256), 0, stream,
                       ws + WS_Y, W1, b1, ws + WS_HID);
    hipLaunchKernelGGL(k_ffn2, dim3(E / 16), dim3(256), 0, stream,
                       ws + WS_HID, W2, b2, ws + WS_O2, out);
}

// Round 5
// 866.809 us; speedup vs baseline: 1.2566x; 1.2566x over previous
//
#include <hip/hip_runtime.h>
#include <hip/hip_bf16.h>
#include <math.h>

#define BSZ 8
#define NLVL 4
#define E 512
#define H 8
#define D 64
#define FFN 2048
#define NNZ 131072
#define NQ 32
#define P32 32
#define NEGF -3.0e38f
#define MAXCH 1056          // max level-sorted 128-key chunks: 131072/128 + 32
#define PERM_OFF 2048       // int offset of perm[] in ws
#define WS_FB 139264        // float region start (perm ends at int 138240)

typedef __attribute__((ext_vector_type(8))) short bf16x8;
typedef __attribute__((ext_vector_type(4))) short bf16x4;
typedef __attribute__((ext_vector_type(4))) float f32x4;

// wsi ints: [0..8) batch counts, [8..16) batch offsets, [16..48) bucket counts,
// [48..80) bucket perm starts (128-aligned), [80..112) bucket chunk prefix,
// [112] tot chunks, [116..148) scatter cursors, perm at [PERM_OFF, +136192)
#define WS_QROT  (WS_FB)
#define WS_WSUM  (WS_QROT + NQ*E)
#define WS_OATT  (WS_WSUM + BSZ*P32*E)
#define WS_O2    (WS_OATT + NQ*E)
#define WS_Y     (WS_O2 + NQ*E)
#define WS_HID   (WS_Y + NQ*E)
#define WS_ML    (WS_HID + NQ*FFN)            // [MAXCH][32][2] f32
#define WS_PART  (WS_ML + MAXCH*P32*2)        // [MAXCH][32][512] f32
#define WS_WALL  (WS_PART + (size_t)MAXCH*P32*E)  // bf16 [b][128][512]

__device__ inline short f2bf(float x) {
    __hip_bfloat16 h = __float2bfloat16(x);
    union { __hip_bfloat16 v; short s; } u; u.v = h; return u.s;
}

__device__ inline bf16x8 cvt8(const float* p) {
    float4 x = *(const float4*)p;
    float4 y = *(const float4*)(p + 4);
    union { bf16x8 v; __hip_bfloat162 h[4]; } u;
    u.h[0] = __float22bfloat162_rn(float2{x.x, x.y});
    u.h[1] = __float22bfloat162_rn(float2{x.z, x.w});
    u.h[2] = __float22bfloat162_rn(float2{y.x, y.y});
    u.h[3] = __float22bfloat162_rn(float2{y.z, y.w});
    return u.v;
}

// ---------------- setup: histograms, offsets, level-sort ----------------
__global__ void k_zero(int* wsi) {
    int t = threadIdx.x;
    if (t < 160) wsi[t] = 0;
}

__global__ void k_hist(const int* __restrict__ fb, int* wsi) {
    __shared__ int h[8];
    int t = threadIdx.x;
    if (t < 8) h[t] = 0;
    __syncthreads();
    for (int j = blockIdx.x * 256 + t; j < NNZ; j += gridDim.x * 256)
        atomicAdd(&h[fb[j]], 1);
    __syncthreads();
    if (t < 8) atomicAdd(&wsi[t], h[t]);
}

__global__ void k_off(int* wsi) {
    if (threadIdx.x == 0) {
        int run = 0;
        for (int b = 0; b < 8; b++) { wsi[8 + b] = run; run += wsi[b]; }
    }
}

__global__ void k_bhist(const int* __restrict__ fb, const int* __restrict__ fl,
                        const int* __restrict__ maxlen, int* wsi) {
    __shared__ int h[32];
    int t = threadIdx.x;
    if (t < 32) h[t] = 0;
    __syncthreads();
    int ml0 = maxlen[0];
    for (int j = blockIdx.x * 256 + t; j < NNZ; j += gridDim.x * 256) {
        int bb = fb[j];
        if (j - wsi[8 + bb] < ml0) atomicAdd(&h[bb * 4 + fl[j]], 1);
    }
    __syncthreads();
    if (t < 32) atomicAdd(&wsi[16 + t], h[t]);
}

__global__ void k_boff(int* wsi) {
    if (threadIdx.x == 0) {
        int ps = 0, ch = 0;
        for (int i = 0; i < 32; i++) {
            wsi[48 + i] = ps;
            wsi[80 + i] = ch;
            int n = (wsi[16 + i] + 127) >> 7;
            ps += n * 128;
            ch += n;
        }
        wsi[112] = ch;
    }
}

__global__ void k_scatter(const int* __restrict__ fb, const int* __restrict__ fl,
                          const int* __restrict__ maxlen, int* wsi) {
    __shared__ int lh[32];
    __shared__ int lbase[32];
    int t = threadIdx.x;
    if (t < 32) lh[t] = 0;
    __syncthreads();
    int gid = blockIdx.x * 256 + t;
    int ml0 = maxlen[0];
    int4 fbv = *(const int4*)&fb[gid * 4];
    int4 flv = *(const int4*)&fl[gid * 4];
    int fbs[4] = {fbv.x, fbv.y, fbv.z, fbv.w};
    int fls[4] = {flv.x, flv.y, flv.z, flv.w};
    int bkt[4], rnk[4];
#pragma unroll
    for (int i = 0; i < 4; i++) {
        int j = gid * 4 + i;
        int bb = fbs[i];
        bool keep = (j - wsi[8 + bb]) < ml0;
        bkt[i] = keep ? bb * 4 + fls[i] : -1;
        rnk[i] = keep ? atomicAdd(&lh[bkt[i]], 1) : 0;
    }
    __syncthreads();
    if (t < 32) lbase[t] = atomicAdd(&wsi[116 + t], lh[t]);
    __syncthreads();
#pragma unroll
    for (int i = 0; i < 4; i++)
        if (bkt[i] >= 0)
            wsi[PERM_OFF + wsi[48 + bkt[i]] + lbase[bkt[i]] + rnk[i]] = gid * 4 + i;
}

// ---------------- q = rope(LN(bg) @ Wq) ----------------
__global__ void k_qrot(const float* __restrict__ bg, const float* __restrict__ Wq,
                       const float* __restrict__ rf, const float* __restrict__ g,
                       const float* __restrict__ bb, float* __restrict__ ws) {
    __shared__ float xr[E];
    __shared__ float qrow[E];
    __shared__ float red[8];
    int r = blockIdx.x, t = threadIdx.x;
    float v0 = bg[r * E + t], v1 = bg[r * E + t + 256];
    float s = v0 + v1;
    for (int o = 32; o > 0; o >>= 1) s += __shfl_down(s, o, 64);
    if ((t & 63) == 0) red[t >> 6] = s;
    __syncthreads();
    if (t == 0) red[0] = (red[0] + red[1] + red[2] + red[3]) * (1.0f / E);
    __syncthreads();
    float mu = red[0];
    __syncthreads();
    float d0 = v0 - mu, d1 = v1 - mu;
    s = d0 * d0 + d1 * d1;
    for (int o = 32; o > 0; o >>= 1) s += __shfl_down(s, o, 64);
    if ((t & 63) == 0) red[t >> 6] = s;
    __syncthreads();
    if (t == 0) red[0] = rsqrtf((red[0] + red[1] + red[2] + red[3]) * (1.0f / E) + 1e-5f);
    __syncthreads();
    float rstd = red[0];
    xr[t] = d0 * rstd * g[t] + bb[t];
    xr[t + 256] = d1 * rstd * g[t + 256] + bb[t + 256];
    __syncthreads();
    for (int half = 0; half < 2; half++) {
        int c = t + half * 256;
        float acc = 0.f;
        for (int e = 0; e < E; e++) acc += xr[e] * Wq[e * E + c];
        qrow[c] = acc;
    }
    __syncthreads();
    int c0 = 2 * t, c1 = c0 + 1;
    int h = c0 >> 6, ii = (c0 & 63) >> 1;
    float freq = rf[h * 32 + ii];
    float pos = (float)(r >> 3);
    float a = pos * freq, ca = cosf(a), sa = sinf(a);
    float x1 = qrow[c0], x2 = qrow[c1];
    float* qr = ws + WS_QROT + r * E;
    qr[c0] = x1 * ca - x2 * sa;
    qr[c1] = x1 * sa + x2 * ca;
}

// ---------------- Wall_bf[b][n=lvl*32+l*8+h][e] ----------------
__global__ void k_wtil(const float* __restrict__ Wkv, const float* __restrict__ rf,
                       const float* __restrict__ ws, short* __restrict__ wall) {
    __shared__ float u[D];
    int blk = blockIdx.x;
    int h = blk & 7, lvl = (blk >> 3) & 3, r = blk >> 5;
    int b = r >> 2, l = r & 3;
    int t = threadIdx.x;
    const float* qr = ws + WS_QROT + r * E + h * D;
    if (t < 32) {
        float freq = rf[h * 32 + t];
        float a = (float)lvl * freq;
        float ca = cosf(a), sa = sinf(a);
        float x1 = qr[2 * t], x2 = qr[2 * t + 1];
        u[2 * t] = x1 * ca + x2 * sa;
        u[2 * t + 1] = -x1 * sa + x2 * ca;
    }
    __syncthreads();
    int n = lvl * 32 + l * 8 + h;
    short* wrow_out = wall + ((size_t)(b * 128 + n)) * E;
    for (int rep = 0; rep < 8; rep++) {
        int e = t + rep * 64;
        const float* wrow = Wkv + (size_t)e * (2 * E) + h * D;
        float acc = 0.f;
#pragma unroll
        for (int c = 0; c < D; c++) acc += wrow[c] * u[c];
        wrow_out[e] = f2bf(acc * 0.125f);
    }
}

// ---------------- flash over level-uniform 128-key chunks ----------------
// Block = 4 waves. Wave w: scores its 32 keys vs the chunk-level's 32 wall rows
// (no level masking, no redundancy); PV e-strip [w*128,(w+1)*128).
// 2 barriers per chunk; PV fvT staging is per-wave-private (barrier-free).
#define KSTR 40    // fvT key... e-row stride (shorts), 80B = 16B-multiple
#define PSTR 136   // pbuf key stride (shorts), 272B = 16B-multiple
__global__ __launch_bounds__(256, 3) void k_flash(
    const float* __restrict__ fv, const short* __restrict__ wall,
    const int* __restrict__ wsi, float* __restrict__ part, float* __restrict__ ml) {
    __shared__ short fvT[4 * 128 * KSTR];   // 40960 B: per-wave [128 e][32 keys]
    __shared__ short pbuf[P32 * PSTR];      // 8704 B:  [p][128 keys]
    __shared__ float mbuf[P32 * 4];
    __shared__ float lbuf[P32 * 4];

    int bid = blockIdx.x;
    if (bid >= wsi[112]) return;
    int bucket = 31;
    for (int i = 1; i < 32; i++) if (wsi[80 + i] > bid) { bucket = i - 1; break; }
    int b = bucket >> 2, lvl = bucket & 3;
    int inner = bid - wsi[80 + bucket];
    int pstart = wsi[48 + bucket] + inner * 128;
    int nv = wsi[16 + bucket] - inner * 128;
    nv = nv > 128 ? 128 : nv;
    const int* perm = wsi + PERM_OFF;
    int t = threadIdx.x, w = t >> 6, lane = t & 63, col = lane & 15, quad = lane >> 4;

    // ---- scores: D[32 wall rows][32 own keys], K=512 ----
    int sl0 = w * 32 + col, sl1 = sl0 + 16;
    bool v0 = sl0 < nv, v1 = sl1 < nv;
    int g0 = v0 ? perm[pstart + sl0] : 0;
    int g1 = v1 ? perm[pstart + sl1] : 0;
    g0 = min(max(g0, 0), NNZ - 1);
    g1 = min(max(g1, 0), NNZ - 1);
    const float* fp0 = fv + (size_t)g0 * E + quad * 8;
    const float* fp1 = fv + (size_t)g1 * E + quad * 8;
    const short* wr0 = wall + ((size_t)(b * 128 + lvl * 32 + col)) * E + quad * 8;
    const short* wr1 = wr0 + (size_t)16 * E;
    f32x4 acc_s[2][2];
#pragma unroll
    for (int mt = 0; mt < 2; mt++)
#pragma unroll
        for (int nt = 0; nt < 2; nt++) acc_s[mt][nt] = f32x4{0.f, 0.f, 0.f, 0.f};
#pragma unroll 4
    for (int ks = 0; ks < 16; ks++) {
        int e0 = ks * 32;
        bf16x8 A0 = *(const bf16x8*)(wr0 + e0);
        bf16x8 A1 = *(const bf16x8*)(wr1 + e0);
        bf16x8 B0 = cvt8(fp0 + e0);
        bf16x8 B1 = cvt8(fp1 + e0);
        acc_s[0][0] = __builtin_amdgcn_mfma_f32_16x16x32_bf16(A0, B0, acc_s[0][0], 0, 0, 0);
        acc_s[0][1] = __builtin_amdgcn_mfma_f32_16x16x32_bf16(A0, B1, acc_s[0][1], 0, 0, 0);
        acc_s[1][0] = __builtin_amdgcn_mfma_f32_16x16x32_bf16(A1, B0, acc_s[1][0], 0, 0, 0);
        acc_s[1][1] = __builtin_amdgcn_mfma_f32_16x16x32_bf16(A1, B1, acc_s[1][1], 0, 0, 0);
    }
    // per-wave max per plane -> mbuf
#pragma unroll
    for (int mt = 0; mt < 2; mt++)
#pragma unroll
        for (int r = 0; r < 4; r++) {
            float a0 = v0 ? acc_s[mt][0][r] : NEGF;
            float a1 = v1 ? acc_s[mt][1][r] : NEGF;
            float v = fmaxf(a0, a1);
#pragma unroll
            for (int msk = 1; msk < 16; msk <<= 1) v = fmaxf(v, __shfl_xor(v, msk, 16));
            if (col == 0) mbuf[(mt * 16 + quad * 4 + r) * 4 + w] = v;
        }
    __syncthreads();   // B1
    // chunk max, P~ -> pbuf (bf16), partial l -> lbuf
#pragma unroll
    for (int mt = 0; mt < 2; mt++)
#pragma unroll
        for (int r = 0; r < 4; r++) {
            int p = mt * 16 + quad * 4 + r;
            f32x4 mm = *(const f32x4*)&mbuf[p * 4];
            float mn = fmaxf(fmaxf(mm[0], mm[1]), fmaxf(mm[2], mm[3]));
            float pv0 = v0 ? expf(acc_s[mt][0][r] - mn) : 0.f;
            float pv1 = v1 ? expf(acc_s[mt][1][r] - mn) : 0.f;
            pbuf[p * PSTR + sl0] = f2bf(pv0);
            pbuf[p * PSTR + sl1] = f2bf(pv1);
            float ls = pv0 + pv1;
#pragma unroll
            for (int msk = 1; msk < 16; msk <<= 1) ls += __shfl_xor(ls, msk, 16);
            if (col == 0) lbuf[p * 4 + w] = ls;
        }
    __syncthreads();   // B2
    if (t < 32) {
        f32x4 mm = *(const f32x4*)&mbuf[t * 4];
        float M = fmaxf(fmaxf(mm[0], mm[1]), fmaxf(mm[2], mm[3]));
        float L = lbuf[t * 4] + lbuf[t * 4 + 1] + lbuf[t * 4 + 2] + lbuf[t * 4 + 3];
        ml[((size_t)bid * P32 + t) * 2] = M;
        ml[((size_t)bid * P32 + t) * 2 + 1] = L;
    }
    // ---- PV: O[32 p][own 128-e strip] += P~ @ fv^T, 4 substeps of 32 keys ----
    f32x4 acc_o[2][8];
#pragma unroll
    for (int mt = 0; mt < 2; mt++)
#pragma unroll
        for (int nt = 0; nt < 8; nt++) acc_o[mt][nt] = f32x4{0.f, 0.f, 0.f, 0.f};
    short* fvTw = &fvT[w * 128 * KSTR];
    int pk = lane >> 3, es = lane & 7;
    for (int s = 0; s < 4; s++) {
        if (s * 32 >= nv) break;
        // stage own e-strip of this substep's 32 keys (per-wave private; no barrier)
        int sb = pstart + s * 32 + pk * 4;
        int j0 = min(max(perm[sb + 0], 0), NNZ - 1);
        int j1 = min(max(perm[sb + 1], 0), NNZ - 1);
        int j2 = min(max(perm[sb + 2], 0), NNZ - 1);
        int j3 = min(max(perm[sb + 3], 0), NNZ - 1);
        const float* r0 = fv + (size_t)j0 * E + w * 128 + es * 16;
        const float* r1 = fv + (size_t)j1 * E + w * 128 + es * 16;
        const float* r2 = fv + (size_t)j2 * E + w * 128 + es * 16;
        const float* r3 = fv + (size_t)j3 * E + w * 128 + es * 16;
#pragma unroll
        for (int ii = 0; ii < 4; ii++) {
            float4 x0 = *(const float4*)(r0 + ii * 4);
            float4 x1 = *(const float4*)(r1 + ii * 4);
            float4 x2 = *(const float4*)(r2 + ii * 4);
            float4 x3 = *(const float4*)(r3 + ii * 4);
            const float* a0 = (const float*)&x0;
            const float* a1 = (const float*)&x1;
            const float* a2 = (const float*)&x2;
            const float* a3 = (const float*)&x3;
#pragma unroll
            for (int q = 0; q < 4; q++) {
                int el = es * 16 + ii * 4 + q;
                union { struct { __hip_bfloat162 lo, hi; } h; bf16x4 v; } u;
                u.h.lo = __float22bfloat162_rn(float2{a0[q], a1[q]});
                u.h.hi = __float22bfloat162_rn(float2{a2[q], a3[q]});
                *(bf16x4*)&fvTw[el * KSTR + pk * 4] = u.v;
            }
        }
        bf16x8 Ap0 = *(const bf16x8*)&pbuf[col * PSTR + s * 32 + quad * 8];
        bf16x8 Ap1 = *(const bf16x8*)&pbuf[(16 + col) * PSTR + s * 32 + quad * 8];
#pragma unroll
        for (int nt = 0; nt < 8; nt++) {
            bf16x8 Bf = *(const bf16x8*)&fvTw[(nt * 16 + col) * KSTR + quad * 8];
            acc_o[0][nt] = __builtin_amdgcn_mfma_f32_16x16x32_bf16(Ap0, Bf, acc_o[0][nt], 0, 0, 0);
            acc_o[1][nt] = __builtin_amdgcn_mfma_f32_16x16x32_bf16(Ap1, Bf, acc_o[1][nt], 0, 0, 0);
        }
    }
    // epilogue: partial O
    float* dst = part + (size_t)bid * P32 * E;
#pragma unroll
    for (int mt = 0; mt < 2; mt++)
#pragma unroll
        for (int nt = 0; nt < 8; nt++)
#pragma unroll
            for (int r = 0; r < 4; r++) {
                int p = mt * 16 + quad * 4 + r;
                dst[(size_t)p * E + w * 128 + nt * 16 + col] = acc_o[mt][nt][r];
            }
}

// ---------------- merge chunk partials (LSE) -> wsum[b*32+p][e] ----------------
__global__ void k_merge(const float* __restrict__ part, const float* __restrict__ ml,
                        const int* __restrict__ wsi, float* __restrict__ wsum) {
    __shared__ float wexp[160];
    __shared__ int cids[160];
    int b = blockIdx.x >> 5, p = blockIdx.x & 31;
    int t = threadIdx.x;
    int c0[4], n0[4];
#pragma unroll
    for (int bk = 0; bk < 4; bk++) {
        int bucket = b * 4 + bk;
        c0[bk] = wsi[80 + bucket];
        n0[bk] = (wsi[16 + bucket] + 127) >> 7;
    }
    int tot = n0[0] + n0[1] + n0[2] + n0[3];
    float M = NEGF;
    for (int bk = 0; bk < 4; bk++)
        for (int c = 0; c < n0[bk]; c++)
            M = fmaxf(M, ml[((size_t)(c0[bk] + c) * P32 + p) * 2]);
    float denom = 0.f;
    for (int bk = 0; bk < 4; bk++)
        for (int c = 0; c < n0[bk]; c++) {
            size_t ix = ((size_t)(c0[bk] + c) * P32 + p) * 2;
            denom += ml[ix + 1] * expf(ml[ix] - M);
        }
    if (t < tot) {
        int rem = t, cid = 0;
        for (int bk = 0; bk < 4; bk++) {
            if (rem < n0[bk]) { cid = c0[bk] + rem; break; }
            rem -= n0[bk];
        }
        cids[t] = cid;
        wexp[t] = expf(ml[((size_t)cid * P32 + p) * 2] - M);
    }
    __syncthreads();
    float inv = 1.0f / denom;
    for (int half = 0; half < 2; half++) {
        int e = t + half * 256;
        float acc = 0.f;
        for (int i = 0; i < tot; i++)
            acc += part[((size_t)cids[i] * P32 + p) * E + e] * wexp[i];
        wsum[((size_t)(b * P32 + p)) * E + e] = acc * inv;
    }
}

// ---------------- o_attn[r][c] = wsum[b][l*8+h] . Wv[:, h*64+ch] ----------------
__global__ void k_oproj(const float* __restrict__ wsum, const float* __restrict__ Wkv,
                        float* __restrict__ oatt) {
    __shared__ float Aw[NQ][E];
    int h = blockIdx.x >> 2, ct = blockIdx.x & 3;
    int t = threadIdx.x;
    {
        int rr = t >> 3, x = (t & 7) * 64;
        int row = (rr >> 2) * P32 + (rr & 3) * 8 + h;
#pragma unroll
        for (int q4 = 0; q4 < 16; q4++)
            *(float4*)&Aw[rr][x + q4 * 4] = *(const float4*)&wsum[(size_t)row * E + x + q4 * 4];
    }
    __syncthreads();
#pragma unroll
    for (int rep = 0; rep < 2; rep++) {
        int idx = rep * 256 + t;
        int rr = idx >> 4, cl = idx & 15;
        int c = h * D + ct * 16 + cl;
        float acc = 0.f;
        for (int e = 0; e < E; e++) acc += Aw[rr][e] * Wkv[(size_t)e * (2 * E) + E + c];
        oatt[rr * E + c] = acc;
    }
}

// ---------------- o2 = o_attn @ Wo + bg ----------------
__global__ void k_wo(const float* __restrict__ oatt, const float* __restrict__ Wo,
                     const float* __restrict__ bg, float* __restrict__ o2) {
    __shared__ float Aw[NQ * E];
    int t = threadIdx.x;
#pragma unroll
    for (int q = 0; q < 16; q++) {
        int i = (q * 256 + t) * 4;
        *(float4*)&Aw[i] = *(const float4*)&oatt[i];
    }
    __syncthreads();
    int ct = blockIdx.x;
#pragma unroll
    for (int rep = 0; rep < 4; rep++) {
        int idx = rep * 256 + t;
        int rr = idx >> 5, cl = idx & 31;
        int c = ct * 32 + cl;
        float acc = bg[rr * E + c];
        for (int e = 0; e < E; e++) acc += Aw[rr * E + e] * Wo[(size_t)e * E + c];
        o2[rr * E + c] = acc;
    }
}

// ---------------- LN rows of o2 -> y ----------------
__global__ void k_ln2(const float* __restrict__ o2, const float* __restrict__ g,
                      const float* __restrict__ bb, float* __restrict__ y) {
    __shared__ float red[8];
    int r = blockIdx.x, t = threadIdx.x;
    float v0 = o2[r * E + t], v1 = o2[r * E + t + 256];
    float s = v0 + v1;
    for (int o = 32; o > 0; o >>= 1) s += __shfl_down(s, o, 64);
    if ((t & 63) == 0) red[t >> 6] = s;
    __syncthreads();
    if (t == 0) red[0] = (red[0] + red[1] + red[2] + red[3]) * (1.0f / E);
    __syncthreads();
    float mu = red[0];
    __syncthreads();
    float d0 = v0 - mu, d1 = v1 - mu;
    s = d0 * d0 + d1 * d1;
    for (int o = 32; o > 0; o >>= 1) s += __shfl_down(s, o, 64);
    if ((t & 63) == 0) red[t >> 6] = s;
    __syncthreads();
    if (t == 0) red[0] = rsqrtf((red[0] + red[1] + red[2] + red[3]) * (1.0f / E) + 1e-5f);
    __syncthreads();
    float rstd = red[0];
    y[r * E + t] = d0 * rstd * g[t] + bb[t];
    y[r * E + t + 256] = d1 * rstd * g[t + 256] + bb[t + 256];
}

// ---------------- hid = relu(y @ W1 + b1) ----------------
__global__ void k_ffn1(const float* __restrict__ y, const float* __restrict__ W1,
                       const float* __restrict__ b1, float* __restrict__ hid) {
    __shared__ float Aw[NQ * E];
    int t = threadIdx.x;
#pragma unroll
    for (int q = 0; q < 16; q++) {
        int i = (q * 256 + t) * 4;
        *(float4*)&Aw[i] = *(const float4*)&y[i];
    }
    __syncthreads();
    int ft = blockIdx.x;
#pragma unroll
    for (int rep = 0; rep < 4; rep++) {
        int idx = rep * 256 + t;
        int rr = idx >> 5, fl = idx & 31;
        int f = ft * 32 + fl;
        float acc = b1[f];
        for (int e = 0; e < E; e++) acc += Aw[rr * E + e] * W1[(size_t)e * FFN + f];
        hid[rr * FFN + f] = fmaxf(acc, 0.f);
    }
}

// ---------------- out = o2 + hid @ W2 + b2 ----------------
__global__ void k_ffn2(const float* __restrict__ hid, const float* __restrict__ W2,
                       const float* __restrict__ b2, const float* __restrict__ o2,
                       float* __restrict__ out) {
    int ct = blockIdx.x;
    int t = threadIdx.x;
#pragma unroll
    for (int rep = 0; rep < 2; rep++) {
        int idx = rep * 256 + t;
        int rr = idx >> 4, cl = idx & 15;
        int c = ct * 16 + cl;
        float acc = b2[c] + o2[rr * E + c];
        for (int f = 0; f < FFN; f++) acc += hid[rr * FFN + f] * W2[(size_t)f * E + c];
        out[rr * E + c] = acc;
    }
}

extern "C" void kernel_launch(void* const* d_in, const int* in_sizes, int n_in,
                              void* d_out, int out_size, void* d_ws, size_t ws_size,
                              hipStream_t stream) {
    const float* bg  = (const float*)d_in[0];
    const float* fv  = (const float*)d_in[1];
    const int*   fb  = (const int*)d_in[2];
    const int*   fl  = (const int*)d_in[3];
    const float* Wq  = (const float*)d_in[4];
    const float* Wkv = (const float*)d_in[5];
    const float* Wo  = (const float*)d_in[6];
    const float* rf  = (const float*)d_in[7];
    const float* lag = (const float*)d_in[8];
    const float* lab = (const float*)d_in[9];
    const float* lfg = (const float*)d_in[10];
    const float* lfb = (const float*)d_in[11];
    const float* W1  = (const float*)d_in[12];
    const float* b1  = (const float*)d_in[13];
    const float* W2  = (const float*)d_in[14];
    const float* b2  = (const float*)d_in[15];
    const int* maxlen = (const int*)d_in[16];
    float* ws = (float*)d_ws;
    int* wsi = (int*)d_ws;
    short* wall = (short*)(ws + WS_WALL);
    float* out = (float*)d_out;

    hipLaunchKernelGGL(k_zero, dim3(1), dim3(256), 0, stream, wsi);
    hipLaunchKernelGGL(k_hist, dim3(128), dim3(256), 0, stream, fb, wsi);
    hipLaunchKernelGGL(k_off, dim3(1), dim3(64), 0, stream, wsi);
    hipLaunchKernelGGL(k_bhist, dim3(128), dim3(256), 0, stream, fb, fl, maxlen, wsi);
    hipLaunchKernelGGL(k_boff, dim3(1), dim3(64), 0, stream, wsi);
    hipLaunchKernelGGL(k_scatter, dim3(128), dim3(256), 0, stream, fb, fl, maxlen, wsi);
    hipLaunchKernelGGL(k_qrot, dim3(NQ), dim3(256), 0, stream, bg, Wq, rf, lag, lab, ws);
    hipLaunchKernelGGL(k_wtil, dim3(NQ * NLVL * H), dim3(64), 0, stream, Wkv, rf, ws, wall);
    hipLaunchKernelGGL(k_flash, dim3(MAXCH), dim3(256), 0, stream,
                       fv, wall, wsi, ws + WS_PART, ws + WS_ML);
    hipLaunchKernelGGL(k_merge, dim3(BSZ * P32), dim3(256), 0, stream,
                       ws + WS_PART, ws + WS_ML, wsi, ws + WS_WSUM);
    hipLaunchKernelGGL(k_oproj, dim3(H * 4), dim3(256), 0, stream,
                       ws + WS_WSUM, Wkv, ws + WS_OATT);
    hipLaunchKernelGGL(k_wo, dim3(16), dim3(256), 0, stream,
                       ws + WS_OATT, Wo, bg, ws + WS_O2);
    hipLaunchKernelGGL(k_ln2, dim3(NQ), dim3(256), 0, stream,
                       ws + WS_O2, lfg, lfb, ws + WS_Y);
    hipLaunchKernelGGL(k_ffn1, dim3(FFN / 32), dim3(256), 0, stream,
                       ws + WS_Y, W1, b1, ws + WS_HID);
    hipLaunchKernelGGL(k_ffn2, dim3(E / 16), dim3(256), 0, stream,
                       ws + WS_HID, W2, b2, ws + WS_O2, out);
}